// Round 4
// baseline (221.470 us; speedup 1.0000x reference)
//
#include <hip/hip_runtime.h>

typedef unsigned short u16;
typedef __bf16 bf16x8 __attribute__((ext_vector_type(8)));
typedef float f32x4 __attribute__((ext_vector_type(4)));

#define BATCH 2
#define NSEQ  2048
#define DIMN  1024
#define NH    16
#define DH    64
#define M_    (BATCH * NSEQ)   // 4096 rows of x
#define E_    (3 * DIMN)       // 3072 qkv features
#define K_    DIMN             // 1024 reduction dim
#define QKV_BYTES ((size_t)M_ * E_ * sizeof(u16))
#define XB_ELEMS  ((size_t)M_ * K_)
#define WB_ELEMS  ((size_t)E_ * K_)
#define VT_BYTES  ((size_t)BATCH * NH * DH * NSEQ * sizeof(u16))     // 8.4 MB
#define NEED2     (QKV_BYTES + (XB_ELEMS + WB_ELEMS) * sizeof(u16))  // 39.8 MB
#define NEED3     (NEED2 + VT_BYTES)                                 // 48.2 MB

__device__ __forceinline__ u16 f2bf(float f) {
  union { float f; unsigned u; } v; v.f = f;
  unsigned r = v.u + 0x7fffu + ((v.u >> 16) & 1u);
  return (u16)(r >> 16);
}
__device__ __forceinline__ uint4 pack8(const float4 a, const float4 b) {
  union { u16 h[8]; uint4 q; } p;
  p.h[0] = f2bf(a.x); p.h[1] = f2bf(a.y); p.h[2] = f2bf(a.z); p.h[3] = f2bf(a.w);
  p.h[4] = f2bf(b.x); p.h[5] = f2bf(b.y); p.h[6] = f2bf(b.z); p.h[7] = f2bf(b.w);
  return p.q;
}
__device__ __forceinline__ void async16(const void* g, void* lds) {
  __builtin_amdgcn_global_load_lds(
      (const __attribute__((address_space(1))) void*)g,
      (__attribute__((address_space(3))) void*)lds, 16, 0, 0);
}

// ---------------------------------------------------------------------------
// Kernel 0: one-shot fp32 -> bf16 convert of X and W (memory-bound).
// ---------------------------------------------------------------------------
__global__ __launch_bounds__(256, 4)
void convert_bf16(const float* __restrict__ X, const float* __restrict__ W,
                  u16* __restrict__ Xb, u16* __restrict__ Wb) {
  const size_t nx = XB_ELEMS / 8, nw = WB_ELEMS / 8;
  const size_t stride = (size_t)gridDim.x * blockDim.x;
  for (size_t i = blockIdx.x * blockDim.x + threadIdx.x; i < nx; i += stride) {
    const float4 a = *(const float4*)&X[i * 8];
    const float4 b = *(const float4*)&X[i * 8 + 4];
    *(uint4*)&Xb[i * 8] = pack8(a, b);
  }
  for (size_t i = blockIdx.x * blockDim.x + threadIdx.x; i < nw; i += stride) {
    const float4 a = *(const float4*)&W[i * 8];
    const float4 b = *(const float4*)&W[i * 8 + 4];
    *(uint4*)&Wb[i * 8] = pack8(a, b);
  }
}

// ---------------------------------------------------------------------------
// Kernel 1: bf16 MFMA GEMM (128x128 tile, BK=64, global_load_lds staging,
// XCD-bijective block swizzle).
// r4 change: __launch_bounds__(256, 3). 768 blocks at 3 blocks/CU = whole
// grid co-resident in ONE dispatch round (768 = 3*256): removes the 1.5-round
// tail (last 256 blocks ran at 1/CU = half speed) and adds a 3rd wave/SIMD of
// latency hiding. VGPR cap at 3 waves/EU = 170; m97's identical structure
// measured 164.
// ---------------------------------------------------------------------------
__global__ __launch_bounds__(256, 3)
void qkv_gemm_a(const u16* __restrict__ Xb, const u16* __restrict__ Wb,
                u16* __restrict__ QKV, u16* __restrict__ VTg) {
  __shared__ __align__(16) u16 As[128 * 64];
  __shared__ __align__(16) u16 Bs[128 * 64];
  const int tid  = threadIdx.x;
  const int wave = tid >> 6, lane = tid & 63;
  // XCD swizzle: lin -> (xcd chunk of 96), m fastest within chunk.
  const int lin = blockIdx.y * gridDim.x + blockIdx.x;   // 0..767
  const int nl  = (lin & 7) * 96 + (lin >> 3);           // bijective (768%8==0)
  const int m0 = (nl & 31) * 128;                        // gridDim.x == 32
  const int n0 = (nl >> 5) * 128;
  const int wm = (wave >> 1) * 64;
  const int wn = (wave & 1) * 64;
  const int lcol = lane & 15, lrow = lane >> 4;
  const int lr8 = lane >> 3;
  const int slog = (lane & 7) ^ lr8;

  f32x4 acc[4][4] = {};

  for (int k0 = 0; k0 < K_; k0 += 64) {
    __syncthreads();
    #pragma unroll
    for (int i = 0; i < 4; ++i) {
      const int g = wave * 4 + i;
      const int r = g * 8 + lr8;
      async16(Xb + (size_t)(m0 + r) * K_ + k0 + slog * 8, &As[g * 512]);
      async16(Wb + (size_t)(n0 + r) * K_ + k0 + slog * 8, &Bs[g * 512]);
    }
    __syncthreads();
    #pragma unroll
    for (int ks = 0; ks < 64; ks += 32) {
      const int segl = (ks >> 3) + lrow;
      bf16x8 af[4], bfr[4];
      #pragma unroll
      for (int i = 0; i < 4; ++i) {
        const int r = wm + lcol + 16 * i;
        af[i] = *(const bf16x8*)&As[r * 64 + ((segl ^ (r & 7)) * 8)];
      }
      #pragma unroll
      for (int j = 0; j < 4; ++j) {
        const int r = wn + lcol + 16 * j;
        bfr[j] = *(const bf16x8*)&Bs[r * 64 + ((segl ^ (r & 7)) * 8)];
      }
      #pragma unroll
      for (int i = 0; i < 4; ++i)
        #pragma unroll
        for (int j = 0; j < 4; ++j)
          acc[i][j] = __builtin_amdgcn_mfma_f32_16x16x32_bf16(
              af[i], bfr[j], acc[i][j], 0, 0, 0);
    }
  }

  if (n0 >= 2 * DIMN) {
    // V third -> VTg[b][h][d][n], 4 consecutive n packed per 8B store.
    #pragma unroll
    for (int i = 0; i < 4; ++i)
      #pragma unroll
      for (int j = 0; j < 4; ++j) {
        const int gm = m0 + wm + 16 * i + lrow * 4;  // n base (4 consecutive)
        const int bb = gm >> 11, n = gm & (NSEQ - 1);
        const int f = (n0 - 2 * DIMN) + wn + 16 * j + lcol;  // 0..1023
        const int h = f >> 6, dd = f & (DH - 1);
        union { u16 h4[4]; uint2 q; } pk;
        #pragma unroll
        for (int r = 0; r < 4; ++r) pk.h4[r] = f2bf(acc[i][j][r]);
        *(uint2*)&VTg[(((size_t)bb * NH + h) * DH + dd) * NSEQ + n] = pk.q;
      }
  } else {
    #pragma unroll
    for (int i = 0; i < 4; ++i)
      #pragma unroll
      for (int j = 0; j < 4; ++j)
        #pragma unroll
        for (int r = 0; r < 4; ++r) {
          const int gm = m0 + wm + 16 * i + lrow * 4 + r;
          const int gn = n0 + wn + 16 * j + lcol;
          QKV[(size_t)gm * E_ + gn] = f2bf(acc[i][j][r]);
        }
  }
}

// Fallback GEMM (fused fp32->bf16 staging, writes full QKV row-major).
__global__ __launch_bounds__(256, 2)
void qkv_gemm_f(const float* __restrict__ X, const float* __restrict__ W,
                u16* __restrict__ QKV) {
  __shared__ __align__(16) u16 As[128 * 64];
  __shared__ __align__(16) u16 Bs[128 * 64];
  const int tid  = threadIdx.x;
  const int wave = tid >> 6, lane = tid & 63;
  const int m0 = blockIdx.x * 128, n0 = blockIdx.y * 128;
  const int wm = (wave >> 1) * 64, wn = (wave & 1) * 64;
  const int lcol = lane & 15, lrow = lane >> 4;
  f32x4 acc[4][4] = {};
  for (int k0 = 0; k0 < K_; k0 += 64) {
    __syncthreads();
    #pragma unroll
    for (int p = 0; p < 4; ++p) {
      const int linear = p * 256 + tid;
      const int r = linear >> 3, s = linear & 7;
      const float4 a0 = *(const float4*)&X[(size_t)(m0 + r) * K_ + k0 + s * 8];
      const float4 a1 = *(const float4*)&X[(size_t)(m0 + r) * K_ + k0 + s * 8 + 4];
      const float4 b0 = *(const float4*)&W[(size_t)(n0 + r) * K_ + k0 + s * 8];
      const float4 b1 = *(const float4*)&W[(size_t)(n0 + r) * K_ + k0 + s * 8 + 4];
      const int ph = (s ^ (r & 7)) * 8;
      *(uint4*)&As[r * 64 + ph] = pack8(a0, a1);
      *(uint4*)&Bs[r * 64 + ph] = pack8(b0, b1);
    }
    __syncthreads();
    #pragma unroll
    for (int ks = 0; ks < 64; ks += 32) {
      const int segl = (ks >> 3) + lrow;
      bf16x8 af[4], bfr[4];
      #pragma unroll
      for (int i = 0; i < 4; ++i) {
        const int r = wm + lcol + 16 * i;
        af[i] = *(const bf16x8*)&As[r * 64 + ((segl ^ (r & 7)) * 8)];
      }
      #pragma unroll
      for (int j = 0; j < 4; ++j) {
        const int r = wn + lcol + 16 * j;
        bfr[j] = *(const bf16x8*)&Bs[r * 64 + ((segl ^ (r & 7)) * 8)];
      }
      #pragma unroll
      for (int i = 0; i < 4; ++i)
        #pragma unroll
        for (int j = 0; j < 4; ++j)
          acc[i][j] = __builtin_amdgcn_mfma_f32_16x16x32_bf16(
              af[i], bfr[j], acc[i][j], 0, 0, 0);
    }
  }
  #pragma unroll
  for (int i = 0; i < 4; ++i)
    #pragma unroll
    for (int j = 0; j < 4; ++j)
      #pragma unroll
      for (int r = 0; r < 4; ++r) {
        const int gm = m0 + wm + 16 * i + lrow * 4 + r;
        const int gn = n0 + wn + 16 * j + lcol;
        QKV[(size_t)gm * E_ + gn] = f2bf(acc[i][j][r]);
      }
}

// ---------------------------------------------------------------------------
// Kernel 2 (r4): MFMA flash attention, ZERO K/V LDS, barrier-free.
// Evidence model (r1: 2x occupancy -> 0 gain; r0 arithmetic: ~550 LDS-cyc of
// ~640/wave-iter): the per-CU LDS pipe is the roofline. Fix: delete LDS work.
// Key fact: the MFMA B-frag wants 8 CONSECUTIVE k-elements at one column --
// for QK^T that is K[j][dim] (contiguous in QKV rows), for PV it is V^T[d][j]
// (contiguous in VTg rows). So B-frags load DIRECTLY from global (L2-resident:
// 512 KB K+V per (b,h); XCD-grouped bh mapping keeps 4 bh = 2 MB per XCD L2).
//   - No Ks/Vs LDS, no staging, and NO __syncthreads AT ALL (Ps is per-wave
//     private) -> waves drift freely, hiding L2 latency.
//   - K/V double-buffered in registers; prefetch issued right after last use.
//   - Ps path kept BIT-EXACT from the proven r0 kernel (scatter w + b128 r).
//   - s_setprio(1) around MFMA clusters (T5, m191: +4-7% on attn).
// LDS insts/thread-iter: 70 (r0) -> 36.
// ---------------------------------------------------------------------------
__global__ __launch_bounds__(256, 2)
void attn4(const u16* __restrict__ QKV, const u16* __restrict__ VTg,
           float* __restrict__ Out) {
  __shared__ __align__(16) u16 Ps[4][32 * 72];   // per-wave [q_local][j]

  const int tid = threadIdx.x, wave = tid >> 6, lane = tid & 63;
  // XCD-grouped mapping: xcd = bid&7 (empirical round-robin), 4 bh per XCD.
  const int bid = blockIdx.x;
  const int xcd = bid & 7, idx = bid >> 3;
  const int bh = xcd * 4 + (idx & 3);            // bijective over 0..511
  const int b = bh >> 4, h = bh & 15;
  const int i0 = (idx >> 2) * 128;
  const int lcol = lane & 15, lrow = lane >> 4;
  const size_t base = (size_t)b * NSEQ;
  const int qoff = h * DH, koff = DIMN + h * DH;
  const size_t vbh = ((size_t)b * NH + h) * DH;  // VTg row base (d rows)

  bf16x8 ones;
  #pragma unroll
  for (int t = 0; t < 8; ++t) ones[t] = (__bf16)1.0f;

  // Q fragments straight from global (once)
  bf16x8 aq[2][2];
  #pragma unroll
  for (int qi = 0; qi < 2; ++qi)
    #pragma unroll
    for (int ksi = 0; ksi < 2; ++ksi) {
      const int row = i0 + wave * 32 + qi * 16 + lcol;
      aq[qi][ksi] = *(const bf16x8*)&QKV[(base + row) * E_ + qoff +
                                         (ksi * 4 + lrow) * 8];
    }

  // K/V B-frag register double-buffer.
  // kreg[ksi*4+jt]: K[j0 + jt*16 + lcol][(ksi*4+lrow)*8 ..+8]
  // vreg[ksi*4+dt]: V^T[dt*16 + lcol][j0 + (ksi*4+lrow)*8 ..+8]
  uint4 kreg[8], vreg[8];
  #pragma unroll
  for (int ksi = 0; ksi < 2; ++ksi) {
    const int seg = ksi * 4 + lrow;
    #pragma unroll
    for (int jt = 0; jt < 4; ++jt)
      kreg[ksi * 4 + jt] =
          *(const uint4*)&QKV[(base + jt * 16 + lcol) * E_ + koff + seg * 8];
    #pragma unroll
    for (int dt = 0; dt < 4; ++dt)
      vreg[ksi * 4 + dt] =
          *(const uint4*)&VTg[(vbh + dt * 16 + lcol) * NSEQ + seg * 8];
  }

  f32x4 o[2][4] = {};
  f32x4 lacc[2] = {};

  for (int j0 = 0; j0 < NSEQ; j0 += 64) {
    // ---- S = Q K^T from register B-frags ----
    f32x4 s[2][4] = {};
    __builtin_amdgcn_s_setprio(1);
    #pragma unroll
    for (int ksi = 0; ksi < 2; ++ksi)
      #pragma unroll
      for (int jt = 0; jt < 4; ++jt) {
        union { uint4 q; bf16x8 v; } bk; bk.q = kreg[ksi * 4 + jt];
        #pragma unroll
        for (int qi = 0; qi < 2; ++qi)
          s[qi][jt] = __builtin_amdgcn_mfma_f32_16x16x32_bf16(
              aq[qi][ksi], bk.v, s[qi][jt], 0, 0, 0);
      }
    __builtin_amdgcn_s_setprio(0);

    // prefetch next K tile (latency covered by softmax + PV)
    if (j0 + 64 < NSEQ) {
      #pragma unroll
      for (int ksi = 0; ksi < 2; ++ksi) {
        const int seg = ksi * 4 + lrow;
        #pragma unroll
        for (int jt = 0; jt < 4; ++jt)
          kreg[ksi * 4 + jt] = *(const uint4*)
              &QKV[(base + j0 + 64 + jt * 16 + lcol) * E_ + koff + seg * 8];
      }
    }

    // ---- static-base softmax numerator -> Ps (r0 bit-exact path) ----
    #pragma unroll
    for (int qi = 0; qi < 2; ++qi)
      #pragma unroll
      for (int jt = 0; jt < 4; ++jt)
        #pragma unroll
        for (int r = 0; r < 4; ++r) {
          const float p = __expf(fmaf(s[qi][jt][r], 0.125f, -12.0f));
          Ps[wave][(qi * 16 + lrow * 4 + r) * 72 + jt * 16 + lcol] = f2bf(p);
        }

    // ---- O += P@V ; l += P@1 (bv from registers) ----
    #pragma unroll
    for (int ksi = 0; ksi < 2; ++ksi) {
      const int seg = ksi * 4 + lrow;
      bf16x8 ap[2];
      #pragma unroll
      for (int qi = 0; qi < 2; ++qi)
        ap[qi] = *(const bf16x8*)&Ps[wave][(qi * 16 + lcol) * 72 + seg * 8];
      __builtin_amdgcn_s_setprio(1);
      #pragma unroll
      for (int dt = 0; dt < 4; ++dt) {
        union { uint4 q; bf16x8 v; } bv; bv.q = vreg[ksi * 4 + dt];
        #pragma unroll
        for (int qi = 0; qi < 2; ++qi)
          o[qi][dt] = __builtin_amdgcn_mfma_f32_16x16x32_bf16(
              ap[qi], bv.v, o[qi][dt], 0, 0, 0);
      }
      #pragma unroll
      for (int qi = 0; qi < 2; ++qi)
        lacc[qi] = __builtin_amdgcn_mfma_f32_16x16x32_bf16(
            ap[qi], ones, lacc[qi], 0, 0, 0);
      __builtin_amdgcn_s_setprio(0);
    }

    // prefetch next V tile (latency covered by next QK + softmax)
    if (j0 + 64 < NSEQ) {
      #pragma unroll
      for (int ksi = 0; ksi < 2; ++ksi) {
        const int seg = ksi * 4 + lrow;
        #pragma unroll
        for (int dt = 0; dt < 4; ++dt)
          vreg[ksi * 4 + dt] = *(const uint4*)
              &VTg[(vbh + dt * 16 + lcol) * NSEQ + j0 + 64 + seg * 8];
      }
    }
  }

  // epilogue: FP32 out[b, n*H + h, d] = o / l
  #pragma unroll
  for (int qi = 0; qi < 2; ++qi)
    #pragma unroll
    for (int r = 0; r < 4; ++r) {
      const float inv = 1.0f / lacc[qi][r];
      const int i = i0 + wave * 32 + qi * 16 + lrow * 4 + r;
      #pragma unroll
      for (int dt = 0; dt < 4; ++dt) {
        const int d = dt * 16 + lcol;
        Out[((base + i) * NH + h) * DH + d] = o[qi][dt][r] * inv;
      }
    }
}

// Fallback single-pass attention (reads V row-major from QKV, LDS scatter).
__global__ __launch_bounds__(256, 2)
void attn(const u16* __restrict__ QKV, float* __restrict__ Out) {
  __shared__ __align__(16) u16 Ks[64 * 72];
  __shared__ __align__(16) u16 Vt[64 * 72];
  __shared__ __align__(16) u16 Ps[4][32 * 72];

  const int tid = threadIdx.x, wave = tid >> 6, lane = tid & 63;
  const int b = blockIdx.x >> 4, h = blockIdx.x & 15;
  const int i0 = blockIdx.y * 128;
  const int lcol = lane & 15, lrow = lane >> 4;
  const size_t base = (size_t)b * NSEQ;
  const int qoff = h * DH, koff = DIMN + h * DH, voff = 2 * DIMN + h * DH;
  const int sr = tid >> 3;
  const int sg = tid & 7;

  bf16x8 ones;
  #pragma unroll
  for (int t = 0; t < 8; ++t) ones[t] = (__bf16)1.0f;

  bf16x8 aq[2][2];
  #pragma unroll
  for (int qi = 0; qi < 2; ++qi)
    #pragma unroll
    for (int ksi = 0; ksi < 2; ++ksi) {
      const int row = i0 + wave * 32 + qi * 16 + lcol;
      aq[qi][ksi] = *(const bf16x8*)&QKV[(base + row) * E_ + qoff +
                                         (ksi * 4 + lrow) * 8];
    }

  uint4 kreg[2], vreg[2];
  #pragma unroll
  for (int p = 0; p < 2; ++p) {
    const int row = p * 32 + sr;
    const u16* src = &QKV[(base + row) * E_];
    kreg[p] = *(const uint4*)&src[koff + sg * 8];
    vreg[p] = *(const uint4*)&src[voff + sg * 8];
  }

  f32x4 o[2][4] = {};
  f32x4 lacc[2] = {};

  for (int j0 = 0; j0 < NSEQ; j0 += 64) {
    __syncthreads();
    #pragma unroll
    for (int p = 0; p < 2; ++p) {
      const int row = p * 32 + sr;
      *(uint4*)&Ks[row * 72 + sg * 8] = kreg[p];
      const u16* pv = (const u16*)&vreg[p];
      const int jseg = (row >> 3) & 7, jlo = row & 7;
      #pragma unroll
      for (int t = 0; t < 8; ++t)
        Vt[(sg * 8 + t) * 72 + (((jseg ^ sg) & 7) * 8 + jlo)] = pv[t];
    }
    __syncthreads();

    if (j0 + 64 < NSEQ) {
      #pragma unroll
      for (int p = 0; p < 2; ++p) {
        const int row = p * 32 + sr;
        const u16* src = &QKV[(base + j0 + 64 + row) * E_];
        kreg[p] = *(const uint4*)&src[koff + sg * 8];
        vreg[p] = *(const uint4*)&src[voff + sg * 8];
      }
    }

    f32x4 s[2][4] = {};
    #pragma unroll
    for (int ksi = 0; ksi < 2; ++ksi) {
      const int seg = ksi * 4 + lrow;
      #pragma unroll
      for (int jt = 0; jt < 4; ++jt) {
        const bf16x8 bk = *(const bf16x8*)&Ks[(jt * 16 + lcol) * 72 + seg * 8];
        #pragma unroll
        for (int qi = 0; qi < 2; ++qi)
          s[qi][jt] = __builtin_amdgcn_mfma_f32_16x16x32_bf16(
              aq[qi][ksi], bk, s[qi][jt], 0, 0, 0);
      }
    }

    #pragma unroll
    for (int qi = 0; qi < 2; ++qi)
      #pragma unroll
      for (int jt = 0; jt < 4; ++jt)
        #pragma unroll
        for (int r = 0; r < 4; ++r) {
          const float p = __expf(fmaf(s[qi][jt][r], 0.125f, -12.0f));
          Ps[wave][(qi * 16 + lrow * 4 + r) * 72 + jt * 16 + lcol] = f2bf(p);
        }

    #pragma unroll
    for (int ksi = 0; ksi < 2; ++ksi) {
      const int seg = ksi * 4 + lrow;
      bf16x8 ap[2];
      #pragma unroll
      for (int qi = 0; qi < 2; ++qi)
        ap[qi] = *(const bf16x8*)&Ps[wave][(qi * 16 + lcol) * 72 + seg * 8];
      #pragma unroll
      for (int dt = 0; dt < 4; ++dt) {
        const int d = dt * 16 + lcol;
        const bf16x8 bv = *(const bf16x8*)&Vt[d * 72 + (((seg ^ (d >> 3)) & 7) * 8)];
        #pragma unroll
        for (int qi = 0; qi < 2; ++qi)
          o[qi][dt] = __builtin_amdgcn_mfma_f32_16x16x32_bf16(
              ap[qi], bv, o[qi][dt], 0, 0, 0);
      }
      #pragma unroll
      for (int qi = 0; qi < 2; ++qi)
        lacc[qi] = __builtin_amdgcn_mfma_f32_16x16x32_bf16(
            ap[qi], ones, lacc[qi], 0, 0, 0);
    }
  }

  #pragma unroll
  for (int qi = 0; qi < 2; ++qi)
    #pragma unroll
    for (int r = 0; r < 4; ++r) {
      const float inv = 1.0f / lacc[qi][r];
      const int i = i0 + wave * 32 + qi * 16 + lrow * 4 + r;
      #pragma unroll
      for (int dt = 0; dt < 4; ++dt) {
        const int d = dt * 16 + lcol;
        Out[((base + i) * NH + h) * DH + d] = o[qi][dt][r] * inv;
      }
    }
}

extern "C" void kernel_launch(void* const* d_in, const int* in_sizes, int n_in,
                              void* d_out, int out_size, void* d_ws, size_t ws_size,
                              hipStream_t stream) {
  const float* x = (const float*)d_in[0];   // fp32 (2,2048,1024)
  const float* w = (const float*)d_in[1];   // fp32 (3072,1024)
  u16* qkv = (u16*)d_ws;                    // bf16 scratch (24 MB)
  float* out = (float*)d_out;               // fp32 (2, 2048*16, 64)

  if (ws_size < QKV_BYTES) return;

  if (ws_size >= NEED3) {
    u16* Xb  = (u16*)((char*)d_ws + QKV_BYTES);
    u16* Wb  = Xb + XB_ELEMS;
    u16* VTg = Wb + WB_ELEMS;
    convert_bf16<<<1024, 256, 0, stream>>>(x, w, Xb, Wb);
    qkv_gemm_a<<<dim3(M_ / 128, E_ / 128), 256, 0, stream>>>(Xb, Wb, qkv, VTg);
    attn4<<<BATCH * NH * (NSEQ / 128), 256, 0, stream>>>(qkv, VTg, out);
  } else {
    qkv_gemm_f<<<dim3(M_ / 128, E_ / 128), 256, 0, stream>>>(x, w, qkv);
    attn<<<dim3(BATCH * NH, NSEQ / 128), 256, 0, stream>>>(qkv, out);
  }
}

// Round 5
// 173.966 us; speedup vs baseline: 1.2731x; 1.2731x over previous
//
#include <hip/hip_runtime.h>

typedef unsigned short u16;
typedef __bf16 bf16x8 __attribute__((ext_vector_type(8)));
typedef float f32x4 __attribute__((ext_vector_type(4)));

#define BATCH 2
#define NSEQ  2048
#define DIMN  1024
#define NH    16
#define DH    64
#define M_    (BATCH * NSEQ)   // 4096 rows of x
#define E_    (3 * DIMN)       // 3072 qkv features
#define K_    DIMN             // 1024 reduction dim
#define QKV_BYTES ((size_t)M_ * E_ * sizeof(u16))
#define XB_ELEMS  ((size_t)M_ * K_)
#define WB_ELEMS  ((size_t)E_ * K_)
#define NEED2     (QKV_BYTES + (XB_ELEMS + WB_ELEMS) * sizeof(u16))  // 39.8 MB

__device__ __forceinline__ u16 f2bf(float f) {
  union { float f; unsigned u; } v; v.f = f;
  unsigned r = v.u + 0x7fffu + ((v.u >> 16) & 1u);
  return (u16)(r >> 16);
}
__device__ __forceinline__ uint4 pack8(const float4 a, const float4 b) {
  union { u16 h[8]; uint4 q; } p;
  p.h[0] = f2bf(a.x); p.h[1] = f2bf(a.y); p.h[2] = f2bf(a.z); p.h[3] = f2bf(a.w);
  p.h[4] = f2bf(b.x); p.h[5] = f2bf(b.y); p.h[6] = f2bf(b.z); p.h[7] = f2bf(b.w);
  return p.q;
}
__device__ __forceinline__ void async16(const void* g, void* lds) {
  __builtin_amdgcn_global_load_lds(
      (const __attribute__((address_space(1))) void*)g,
      (__attribute__((address_space(3))) void*)lds, 16, 0, 0);
}

// ---------------------------------------------------------------------------
// Kernel 0: one-shot fp32 -> bf16 convert of X and W (memory-bound).
// ---------------------------------------------------------------------------
__global__ __launch_bounds__(256, 4)
void convert_bf16(const float* __restrict__ X, const float* __restrict__ W,
                  u16* __restrict__ Xb, u16* __restrict__ Wb) {
  const size_t nx = XB_ELEMS / 8, nw = WB_ELEMS / 8;
  const size_t stride = (size_t)gridDim.x * blockDim.x;
  for (size_t i = blockIdx.x * blockDim.x + threadIdx.x; i < nx; i += stride) {
    const float4 a = *(const float4*)&X[i * 8];
    const float4 b = *(const float4*)&X[i * 8 + 4];
    *(uint4*)&Xb[i * 8] = pack8(a, b);
  }
  for (size_t i = blockIdx.x * blockDim.x + threadIdx.x; i < nw; i += stride) {
    const float4 a = *(const float4*)&W[i * 8];
    const float4 b = *(const float4*)&W[i * 8 + 4];
    *(uint4*)&Wb[i * 8] = pack8(a, b);
  }
}

// ---------------------------------------------------------------------------
// Kernel 1 (r5): bf16 MFMA GEMM, m97-pure structure.
//  - VTg epilogue DELETED (r4 evidence: (256,3) gave no speedup -> spills from
//    the scatter epilogue's extra addressing; attn reverts to r0 and doesn't
//    need V^T). Epilogue is now uniform row-major stores = m97-class (164
//    VGPR measured for this structure in learn_hip).
//  - __launch_bounds__(256, 3): 3 blocks/CU -> all 768 blocks co-resident in
//    ONE round (768 = 3*256); kills the half-occupancy 256-block tail that
//    (256,2)'s 1.5 rounds had, and adds a 3rd wave/SIMD of latency hiding
//    (m97 ran at exactly this occupancy for 874-912 TF).
//  - XCD-bijective block swizzle kept (T1).
// ---------------------------------------------------------------------------
__global__ __launch_bounds__(256, 3)
void qkv_gemm_a(const u16* __restrict__ Xb, const u16* __restrict__ Wb,
                u16* __restrict__ QKV) {
  __shared__ __align__(16) u16 As[128 * 64];
  __shared__ __align__(16) u16 Bs[128 * 64];
  const int tid  = threadIdx.x;
  const int wave = tid >> 6, lane = tid & 63;
  // XCD swizzle: lin -> (xcd chunk of 96), m fastest within chunk.
  const int lin = blockIdx.y * gridDim.x + blockIdx.x;   // 0..767
  const int nl  = (lin & 7) * 96 + (lin >> 3);           // bijective (768%8==0)
  const int m0 = (nl & 31) * 128;                        // gridDim.x == 32
  const int n0 = (nl >> 5) * 128;
  const int wm = (wave >> 1) * 64;
  const int wn = (wave & 1) * 64;
  const int lcol = lane & 15, lrow = lane >> 4;
  const int lr8 = lane >> 3;
  const int slog = (lane & 7) ^ lr8;

  f32x4 acc[4][4] = {};

  for (int k0 = 0; k0 < K_; k0 += 64) {
    __syncthreads();
    #pragma unroll
    for (int i = 0; i < 4; ++i) {
      const int g = wave * 4 + i;
      const int r = g * 8 + lr8;
      async16(Xb + (size_t)(m0 + r) * K_ + k0 + slog * 8, &As[g * 512]);
      async16(Wb + (size_t)(n0 + r) * K_ + k0 + slog * 8, &Bs[g * 512]);
    }
    __syncthreads();
    #pragma unroll
    for (int ks = 0; ks < 64; ks += 32) {
      const int segl = (ks >> 3) + lrow;
      bf16x8 af[4], bfr[4];
      #pragma unroll
      for (int i = 0; i < 4; ++i) {
        const int r = wm + lcol + 16 * i;
        af[i] = *(const bf16x8*)&As[r * 64 + ((segl ^ (r & 7)) * 8)];
      }
      #pragma unroll
      for (int j = 0; j < 4; ++j) {
        const int r = wn + lcol + 16 * j;
        bfr[j] = *(const bf16x8*)&Bs[r * 64 + ((segl ^ (r & 7)) * 8)];
      }
      #pragma unroll
      for (int i = 0; i < 4; ++i)
        #pragma unroll
        for (int j = 0; j < 4; ++j)
          acc[i][j] = __builtin_amdgcn_mfma_f32_16x16x32_bf16(
              af[i], bfr[j], acc[i][j], 0, 0, 0);
    }
  }

  #pragma unroll
  for (int i = 0; i < 4; ++i)
    #pragma unroll
    for (int j = 0; j < 4; ++j)
      #pragma unroll
      for (int r = 0; r < 4; ++r) {
        const int gm = m0 + wm + 16 * i + lrow * 4 + r;
        const int gn = n0 + wn + 16 * j + lcol;
        QKV[(size_t)gm * E_ + gn] = f2bf(acc[i][j][r]);
      }
}

// Fallback GEMM (fused fp32->bf16 staging) if ws too small for Xb/Wb.
__global__ __launch_bounds__(256, 2)
void qkv_gemm_f(const float* __restrict__ X, const float* __restrict__ W,
                u16* __restrict__ QKV) {
  __shared__ __align__(16) u16 As[128 * 64];
  __shared__ __align__(16) u16 Bs[128 * 64];
  const int tid  = threadIdx.x;
  const int wave = tid >> 6, lane = tid & 63;
  const int m0 = blockIdx.x * 128, n0 = blockIdx.y * 128;
  const int wm = (wave >> 1) * 64, wn = (wave & 1) * 64;
  const int lcol = lane & 15, lrow = lane >> 4;
  f32x4 acc[4][4] = {};
  for (int k0 = 0; k0 < K_; k0 += 64) {
    __syncthreads();
    #pragma unroll
    for (int p = 0; p < 4; ++p) {
      const int linear = p * 256 + tid;
      const int r = linear >> 3, s = linear & 7;
      const float4 a0 = *(const float4*)&X[(size_t)(m0 + r) * K_ + k0 + s * 8];
      const float4 a1 = *(const float4*)&X[(size_t)(m0 + r) * K_ + k0 + s * 8 + 4];
      const float4 b0 = *(const float4*)&W[(size_t)(n0 + r) * K_ + k0 + s * 8];
      const float4 b1 = *(const float4*)&W[(size_t)(n0 + r) * K_ + k0 + s * 8 + 4];
      const int ph = (s ^ (r & 7)) * 8;
      *(uint4*)&As[r * 64 + ph] = pack8(a0, a1);
      *(uint4*)&Bs[r * 64 + ph] = pack8(b0, b1);
    }
    __syncthreads();
    #pragma unroll
    for (int ks = 0; ks < 64; ks += 32) {
      const int segl = (ks >> 3) + lrow;
      bf16x8 af[4], bfr[4];
      #pragma unroll
      for (int i = 0; i < 4; ++i) {
        const int r = wm + lcol + 16 * i;
        af[i] = *(const bf16x8*)&As[r * 64 + ((segl ^ (r & 7)) * 8)];
      }
      #pragma unroll
      for (int j = 0; j < 4; ++j) {
        const int r = wn + lcol + 16 * j;
        bfr[j] = *(const bf16x8*)&Bs[r * 64 + ((segl ^ (r & 7)) * 8)];
      }
      #pragma unroll
      for (int i = 0; i < 4; ++i)
        #pragma unroll
        for (int j = 0; j < 4; ++j)
          acc[i][j] = __builtin_amdgcn_mfma_f32_16x16x32_bf16(
              af[i], bfr[j], acc[i][j], 0, 0, 0);
    }
  }
  #pragma unroll
  for (int i = 0; i < 4; ++i)
    #pragma unroll
    for (int j = 0; j < 4; ++j)
      #pragma unroll
      for (int r = 0; r < 4; ++r) {
        const int gm = m0 + wm + 16 * i + lrow * 4 + r;
        const int gn = n0 + wn + 16 * j + lcol;
        QKV[(size_t)gm * E_ + gn] = f2bf(acc[i][j][r]);
      }
}

// ---------------------------------------------------------------------------
// Kernel 2 (r5): the PROVEN r0 attention body (85.5 us) with exactly two
// isolated, evidence-backed deltas:
//  (1) Vt row stride 64 -> 72 u16 (36 dw = 4 mod 32 banks): correctness-proven
//      in r1's passing attn_split; measured conflicts 9.4M -> 5.2M there.
//  (2) s_setprio(1) around the MFMA clusters (T5; m191: +4-7% on attn,
//      never yet tested on this structure in isolation).
// Everything else (layouts, staging, softmax, epilogue) is r0 bit-exact.
// ---------------------------------------------------------------------------
__global__ __launch_bounds__(256, 2)
void attn(const u16* __restrict__ QKV, float* __restrict__ Out) {
  __shared__ __align__(16) u16 Ks[64 * 72];
  __shared__ __align__(16) u16 Vt[64 * 72];        // XOR-swizzled, stride 72
  __shared__ __align__(16) u16 Ps[4][32 * 72];     // 32 rows per wave

  const int tid = threadIdx.x, wave = tid >> 6, lane = tid & 63;
  const int b = blockIdx.x >> 4, h = blockIdx.x & 15;
  const int i0 = blockIdx.y * 128;
  const int lcol = lane & 15, lrow = lane >> 4;
  const size_t base = (size_t)b * NSEQ;
  const int qoff = h * DH, koff = DIMN + h * DH, voff = 2 * DIMN + h * DH;
  const int sr = tid >> 3;  // 0..31
  const int sg = tid & 7;

  bf16x8 ones;
  #pragma unroll
  for (int t = 0; t < 8; ++t) ones[t] = (__bf16)1.0f;

  // Q fragments straight from global (once)
  bf16x8 aq[2][2];
  #pragma unroll
  for (int qi = 0; qi < 2; ++qi)
    #pragma unroll
    for (int ksi = 0; ksi < 2; ++ksi) {
      const int row = i0 + wave * 32 + qi * 16 + lcol;
      aq[qi][ksi] = *(const bf16x8*)&QKV[(base + row) * E_ + qoff +
                                         (ksi * 4 + lrow) * 8];
    }

  // prefetch K/V tile 0
  uint4 kreg[2], vreg[2];
  #pragma unroll
  for (int p = 0; p < 2; ++p) {
    const int row = p * 32 + sr;
    const u16* src = &QKV[(base + row) * E_];
    kreg[p] = *(const uint4*)&src[koff + sg * 8];
    vreg[p] = *(const uint4*)&src[voff + sg * 8];
  }

  f32x4 o[2][4] = {};
  f32x4 lacc[2] = {};

  for (int j0 = 0; j0 < NSEQ; j0 += 64) {
    __syncthreads();
    #pragma unroll
    for (int p = 0; p < 2; ++p) {
      const int row = p * 32 + sr;
      *(uint4*)&Ks[row * 72 + sg * 8] = kreg[p];
      const u16* pv = (const u16*)&vreg[p];
      const int jseg = (row >> 3) & 7, jlo = row & 7;
      #pragma unroll
      for (int t = 0; t < 8; ++t)
        Vt[(sg * 8 + t) * 72 + (((jseg ^ sg) & 7) * 8 + jlo)] = pv[t];
    }
    __syncthreads();

    if (j0 + 64 < NSEQ) {
      #pragma unroll
      for (int p = 0; p < 2; ++p) {
        const int row = p * 32 + sr;
        const u16* src = &QKV[(base + j0 + 64 + row) * E_];
        kreg[p] = *(const uint4*)&src[koff + sg * 8];
        vreg[p] = *(const uint4*)&src[voff + sg * 8];
      }
    }

    // S: [2 qi x 16 q] x 64 j — each bk read feeds 2 MFMAs
    f32x4 s[2][4] = {};
    #pragma unroll
    for (int ksi = 0; ksi < 2; ++ksi) {
      const int seg = ksi * 4 + lrow;
      #pragma unroll
      for (int jt = 0; jt < 4; ++jt) {
        const bf16x8 bk = *(const bf16x8*)&Ks[(jt * 16 + lcol) * 72 + seg * 8];
        __builtin_amdgcn_s_setprio(1);
        #pragma unroll
        for (int qi = 0; qi < 2; ++qi)
          s[qi][jt] = __builtin_amdgcn_mfma_f32_16x16x32_bf16(
              aq[qi][ksi], bk, s[qi][jt], 0, 0, 0);
        __builtin_amdgcn_s_setprio(0);
      }
    }

    // static-base softmax numerator -> Ps (A-layout)
    #pragma unroll
    for (int qi = 0; qi < 2; ++qi)
      #pragma unroll
      for (int jt = 0; jt < 4; ++jt)
        #pragma unroll
        for (int r = 0; r < 4; ++r) {
          const float p = __expf(fmaf(s[qi][jt][r], 0.125f, -12.0f));
          Ps[wave][(qi * 16 + lrow * 4 + r) * 72 + jt * 16 + lcol] = f2bf(p);
        }

    // O += P@V ; l += P@1 — each bv read feeds 2 MFMAs
    #pragma unroll
    for (int ksi = 0; ksi < 2; ++ksi) {
      const int seg = ksi * 4 + lrow;
      bf16x8 ap[2];
      #pragma unroll
      for (int qi = 0; qi < 2; ++qi)
        ap[qi] = *(const bf16x8*)&Ps[wave][(qi * 16 + lcol) * 72 + seg * 8];
      __builtin_amdgcn_s_setprio(1);
      #pragma unroll
      for (int dt = 0; dt < 4; ++dt) {
        const int d = dt * 16 + lcol;
        const bf16x8 bv = *(const bf16x8*)&Vt[d * 72 + (((seg ^ (d >> 3)) & 7) * 8)];
        #pragma unroll
        for (int qi = 0; qi < 2; ++qi)
          o[qi][dt] = __builtin_amdgcn_mfma_f32_16x16x32_bf16(
              ap[qi], bv, o[qi][dt], 0, 0, 0);
      }
      #pragma unroll
      for (int qi = 0; qi < 2; ++qi)
        lacc[qi] = __builtin_amdgcn_mfma_f32_16x16x32_bf16(
            ap[qi], ones, lacc[qi], 0, 0, 0);
      __builtin_amdgcn_s_setprio(0);
    }
  }

  // epilogue: FP32 out[b, n*H + h, d] = o / l
  #pragma unroll
  for (int qi = 0; qi < 2; ++qi)
    #pragma unroll
    for (int r = 0; r < 4; ++r) {
      const float inv = 1.0f / lacc[qi][r];
      const int i = i0 + wave * 32 + qi * 16 + lrow * 4 + r;
      #pragma unroll
      for (int dt = 0; dt < 4; ++dt) {
        const int d = dt * 16 + lcol;
        Out[((base + i) * NH + h) * DH + d] = o[qi][dt][r] * inv;
      }
    }
}

extern "C" void kernel_launch(void* const* d_in, const int* in_sizes, int n_in,
                              void* d_out, int out_size, void* d_ws, size_t ws_size,
                              hipStream_t stream) {
  const float* x = (const float*)d_in[0];   // fp32 (2,2048,1024)
  const float* w = (const float*)d_in[1];   // fp32 (3072,1024)
  u16* qkv = (u16*)d_ws;                    // bf16 scratch (24 MB)
  float* out = (float*)d_out;               // fp32 (2, 2048*16, 64)

  if (ws_size < QKV_BYTES) return;

  if (ws_size >= NEED2) {
    u16* Xb = (u16*)((char*)d_ws + QKV_BYTES);
    u16* Wb = Xb + XB_ELEMS;
    convert_bf16<<<1024, 256, 0, stream>>>(x, w, Xb, Wb);
    qkv_gemm_a<<<dim3(M_ / 128, E_ / 128), 256, 0, stream>>>(Xb, Wb, qkv);
  } else {
    qkv_gemm_f<<<dim3(M_ / 128, E_ / 128), 256, 0, stream>>>(x, w, qkv);
  }
  attn<<<dim3(BATCH * NH, NSEQ / 128), 256, 0, stream>>>(qkv, out);
}